// Round 15
// baseline (152.950 us; speedup 1.0000x reference)
//
#include <hip/hip_runtime.h>

// SGCN fused, MFMA v12 = v10 (145.7us) + persistent blocks (grid 512, 4 chunks of
// TB=4 t) + cross-chunk prefetch of a + front-half x during prior phase-1.
// s_lds double-buffered (staging(j+1) vs epilogue(j) race); a_t/g barrier-safe.
// out[n,f,t,w] = sum_c W[c,f]*g[c,w] + b[f]*s[w],  g[c,w] = sum_v x[n,c,t,v]*a[n,t,v,w]
// d_out = out (67,108,864 f32) ++ a (8,388,608 f32);  d_ws = Wt f16 [f][c] (131072 B)

#define NN 128
#define CC 256
#define TT 64
#define VV 32
#define FF 256
#define TB 4
#define NCH 4

typedef _Float16 half8 __attribute__((ext_vector_type(8)));
typedef _Float16 half4 __attribute__((ext_vector_type(4)));
typedef float floatx4 __attribute__((ext_vector_type(4)));

__global__ __launch_bounds__(256) void wt_prep_kernel(const float* __restrict__ W,
                                                      _Float16* __restrict__ Wt) {
    const int c = blockIdx.x;
    const int f = threadIdx.x;
    Wt[f * CC + c] = (_Float16)W[c * FF + f];
}

__global__ __launch_bounds__(512, 2) void sgcn_mfma12_kernel(
    const float* __restrict__ x, const float* __restrict__ a,
    const _Float16* __restrict__ Wt, const float* __restrict__ b,
    float* __restrict__ out, float* __restrict__ out_a)
{
    // a_t: rows (it*32+w), 32 f16 v's, 64B/row, swizzle byte ^= (row&3)<<4
    __shared__ _Float16 a_t[TB * VV * VV];       // 8 KB
    // g: per-t [32 w-rows][256 c] f16, 512B/row, swizzle byte ^= (row&7)<<4
    __shared__ _Float16 g_s[TB * VV * 256];      // 64 KB
    __shared__ float    s_buf[2][TB][VV];        // 1 KB (double-buffered)
    // total 73 KB -> 2 blocks/CU; bounds(512,2) caps VGPR at 128

    const int tid  = threadIdx.x;
    const int lane = tid & 63;
    const int wv   = tid >> 6;       // wave 0..7
    const int l15  = lane & 15;
    const int lg   = lane >> 4;      // 0..3
    const int blk  = blockIdx.x;     // 512 blocks = 2/CU exactly
    const int n    = blk >> 2;       // 4 blocks per n
    const int tgb  = (blk & 3) * NCH;  // first t-group of this block

    char* at_base = (char*)a_t;
    char* g_base  = (char*)g_s;

    const int tA    = wv >> 1;       // phase-1: this wave's t (0..3)
    const int chalf = wv & 1;        // phase-1: c-tile half

    // staging decomposition (same for every chunk)
    const int o0  = tid * 4;                  // k=0 flat f32 offset
    const int o1  = (tid + 512) * 4;          // k=1
    const int it0 = o0 >> 10, r0s = o0 & 1023;
    const int it1 = o1 >> 10, r1s = o1 & 1023;

    // ---- initial prefetch for chunk 0: a (2 x float4) + front-half x (ci 0..3)
    float4 a_nx[2];
    float4 xp[8];
    {
        const int t0 = tgb * TB;
        a_nx[0] = *reinterpret_cast<const float4*>(a + ((size_t)(n * TT + t0 + it0)) * 1024 + r0s);
        a_nx[1] = *reinterpret_cast<const float4*>(a + ((size_t)(n * TT + t0 + it1)) * 1024 + r1s);
        #pragma unroll
        for (int ci = 0; ci < 4; ++ci) {
            const int c = (chalf * 8 + ci) * 16 + l15;
            const float* xpp = x + (((size_t)n * CC + c) * TT + (t0 + tA)) * VV + 8 * lg;
            xp[ci * 2 + 0] = *reinterpret_cast<const float4*>(xpp);
            xp[ci * 2 + 1] = *reinterpret_cast<const float4*>(xpp + 4);
        }
    }

    #pragma unroll 1
    for (int ch = 0; ch < NCH; ++ch) {
        const int t0 = (tgb + ch) * TB;

        // ---- back-half x loads (ci 4..7), hidden under staging + barrier
        float4 xb[8];
        #pragma unroll
        for (int ci = 4; ci < 8; ++ci) {
            const int c = (chalf * 8 + ci) * 16 + l15;
            const float* xpp = x + (((size_t)n * CC + c) * TT + (t0 + tA)) * VV + 8 * lg;
            xb[(ci - 4) * 2 + 0] = *reinterpret_cast<const float4*>(xpp);
            xb[(ci - 4) * 2 + 1] = *reinterpret_cast<const float4*>(xpp + 4);
        }

        // ---- staging: mirror a to out tail + transposed f16 a_t (from prefetched regs)
        #pragma unroll
        for (int k = 0; k < 2; ++k) {
            const int it = k == 0 ? it0 : it1;
            const int rr = k == 0 ? r0s : r1s;
            const int v  = rr >> 5;
            const int w0 = rr & 31;
            const size_t off = ((size_t)(n * TT + t0 + it)) * 1024 + rr;
            float4 av = a_nx[k];
            *reinterpret_cast<float4*>(out_a + off) = av;
            #pragma unroll
            for (int j = 0; j < 4; ++j) {
                const int row = it * VV + w0 + j;
                const float e = j == 0 ? av.x : j == 1 ? av.y : j == 2 ? av.z : av.w;
                *reinterpret_cast<_Float16*>(at_base + row * 64 +
                                             ((v * 2) ^ ((row & 3) << 4))) = (_Float16)e;
            }
        }

        __syncthreads();             // barrier 1: a_t ready

        // ---- s[it][w] -> s_buf[ch&1] (read after barrier 2 of this chunk)
        if (tid < TB * VV) {
            const int it = tid >> 5, w = tid & 31;
            const int row = it * VV + w;
            float ss = 0.0f;
            #pragma unroll
            for (int v = 0; v < VV; ++v)
                ss += (float)*reinterpret_cast<const _Float16*>(
                    at_base + row * 64 + ((v * 2) ^ ((row & 3) << 4)));
            s_buf[ch & 1][it][w] = ss;
        }

        // ---- phase 1: GEMM-A for own t, 8 c-tiles; write swizzled g[tA]
        {
            const int ra = tA * VV + l15, rb = ra + 16;
            half8 bA0 = *reinterpret_cast<const half8*>(at_base + ra * 64 +
                                                        ((16 * lg) ^ ((ra & 3) << 4)));
            half8 bA1 = *reinterpret_cast<const half8*>(at_base + rb * 64 +
                                                        ((16 * lg) ^ ((rb & 3) << 4)));
            char* gt = g_base + tA * (VV * 256 * 2);
            #pragma unroll
            for (int ci = 0; ci < 8; ++ci) {
                const int ct = chalf * 8 + ci;
                float4 x0 = ci < 4 ? xp[ci * 2 + 0] : xb[(ci - 4) * 2 + 0];
                float4 x1 = ci < 4 ? xp[ci * 2 + 1] : xb[(ci - 4) * 2 + 1];
                half8 af;
                af[0] = (_Float16)x0.x; af[1] = (_Float16)x0.y;
                af[2] = (_Float16)x0.z; af[3] = (_Float16)x0.w;
                af[4] = (_Float16)x1.x; af[5] = (_Float16)x1.y;
                af[6] = (_Float16)x1.z; af[7] = (_Float16)x1.w;
                #pragma unroll
                for (int wt = 0; wt < 2; ++wt) {
                    floatx4 acc = {0.f, 0.f, 0.f, 0.f};
                    acc = __builtin_amdgcn_mfma_f32_16x16x32_f16(af, wt ? bA1 : bA0, acc, 0, 0, 0);
                    half4 gh;
                    gh[0] = (_Float16)acc[0]; gh[1] = (_Float16)acc[1];
                    gh[2] = (_Float16)acc[2]; gh[3] = (_Float16)acc[3];
                    const int row = 16 * wt + l15;
                    const int cb  = (ct * 16 + 4 * lg) * 2;
                    *reinterpret_cast<half4*>(gt + row * 512 + (cb ^ ((row & 7) << 4))) = gh;
                }
            }
        }

        // ---- cross-chunk prefetch: a + front-half x for ch+1 (xf regs dead now;
        // latency lands under barrier 2 + phase 2)
        if (ch + 1 < NCH) {
            const int t0n = (tgb + ch + 1) * TB;
            a_nx[0] = *reinterpret_cast<const float4*>(a + ((size_t)(n * TT + t0n + it0)) * 1024 + r0s);
            a_nx[1] = *reinterpret_cast<const float4*>(a + ((size_t)(n * TT + t0n + it1)) * 1024 + r1s);
            #pragma unroll
            for (int ci = 0; ci < 4; ++ci) {
                const int c = (chalf * 8 + ci) * 16 + l15;
                const float* xpp = x + (((size_t)n * CC + c) * TT + (t0n + tA)) * VV + 8 * lg;
                xp[ci * 2 + 0] = *reinterpret_cast<const float4*>(xpp);
                xp[ci * 2 + 1] = *reinterpret_cast<const float4*>(xpp + 4);
            }
        }

        __syncthreads();             // barrier 2: g (all 4 t) + s_buf ready

        // ---- phase 2 (v10 structure): wave owns f-tiles {wv, wv+8}; wb[8]/f-tile
        #pragma unroll
        for (int fth = 0; fth < 2; ++fth) {
            const int ft = fth * 8 + wv;
            const int f  = ft * 16 + l15;
            half8 wb[8];
            const _Float16* wp = Wt + (size_t)f * CC + 8 * lg;
            #pragma unroll
            for (int ks = 0; ks < 8; ++ks)
                wb[ks] = *reinterpret_cast<const half8*>(wp + 32 * ks);
            const float bvf = b[f];

            #pragma unroll
            for (int tt = 0; tt < TB; ++tt) {
                char* gt = g_base + tt * (VV * 256 * 2);
                floatx4 acc2[2];
                acc2[0] = (floatx4){0.f, 0.f, 0.f, 0.f};
                acc2[1] = (floatx4){0.f, 0.f, 0.f, 0.f};

                __builtin_amdgcn_s_setprio(1);
                #pragma unroll
                for (int ks = 0; ks < 8; ++ks) {
                    const int rr0 = l15, rr1 = 16 + l15;
                    const int cb = (32 * ks + 8 * lg) * 2;
                    half8 ga0 = *reinterpret_cast<const half8*>(gt + rr0 * 512 +
                                                                (cb ^ ((rr0 & 7) << 4)));
                    half8 ga1 = *reinterpret_cast<const half8*>(gt + rr1 * 512 +
                                                                (cb ^ ((rr1 & 7) << 4)));
                    acc2[0] = __builtin_amdgcn_mfma_f32_16x16x32_f16(ga0, wb[ks], acc2[0], 0, 0, 0);
                    acc2[1] = __builtin_amdgcn_mfma_f32_16x16x32_f16(ga1, wb[ks], acc2[1], 0, 0, 0);
                }
                __builtin_amdgcn_s_setprio(0);

                float* ob = out + (((size_t)n * FF + f) * TT + (t0 + tt)) * VV;
                #pragma unroll
                for (int mt = 0; mt < 2; ++mt) {
                    const int w0 = 16 * mt + 4 * lg;
                    float4 sv = *reinterpret_cast<const float4*>(&s_buf[ch & 1][tt][w0]);
                    float4 o;
                    o.x = acc2[mt][0] + bvf * sv.x;
                    o.y = acc2[mt][1] + bvf * sv.y;
                    o.z = acc2[mt][2] + bvf * sv.z;
                    o.w = acc2[mt][3] + bvf * sv.w;
                    *reinterpret_cast<float4*>(ob + w0) = o;
                }
            }
        }
        // next chunk's staging (a_t writes) is safe: to get there every wave
        // passed barrier 2 of THIS chunk, and a_t is only read before it.
    }
}

// ---- fallback (verified round-3 scalar kernel): used only if ws too small
__global__ __launch_bounds__(256) void sgcn_fused_kernel(
    const float* __restrict__ x, const float* __restrict__ a,
    const float* __restrict__ W, const float* __restrict__ b,
    float* __restrict__ out, float* __restrict__ out_a)
{
    __shared__ float x_lds[CC][VV];
    __shared__ float a_lds[VV][VV];
    const int tid = threadIdx.x;
    const int nt  = blockIdx.x;
    const int n   = nt >> 6;
    const int t   = nt & 63;
    const float* xb = x + (size_t)n * CC * TT * VV + (size_t)t * VV;
    #pragma unroll
    for (int k = 0; k < 8; ++k) {
        int e = tid * 4 + k * 1024;
        int c = e >> 5, v = e & 31;
        float4 val = *reinterpret_cast<const float4*>(xb + (size_t)c * (TT * VV) + v);
        *reinterpret_cast<float4*>(&x_lds[c][v]) = val;
    }
    {
        const float* ab = a + (size_t)nt * (VV * VV);
        float4 av = *reinterpret_cast<const float4*>(ab + tid * 4);
        *reinterpret_cast<float4*>(&a_lds[0][0] + tid * 4) = av;
        *reinterpret_cast<float4*>(out_a + (size_t)nt * (VV * VV) + tid * 4) = av;
    }
    __syncthreads();
    const int f = tid;
    float h[VV];
    #pragma unroll
    for (int v = 0; v < VV; ++v) h[v] = 0.0f;
    #pragma unroll 4
    for (int c = 0; c < CC; ++c) {
        float wv = W[c * FF + f];
        #pragma unroll
        for (int v = 0; v < VV; ++v) h[v] = fmaf(x_lds[c][v], wv, h[v]);
    }
    const float bias = b[f];
    #pragma unroll
    for (int v = 0; v < VV; ++v) h[v] += bias;
    float o[VV];
    #pragma unroll
    for (int w = 0; w < VV; ++w) o[w] = 0.0f;
    #pragma unroll
    for (int v = 0; v < VV; ++v) {
        float hv = h[v];
        #pragma unroll
        for (int w = 0; w < VV; ++w) o[w] = fmaf(hv, a_lds[v][w], o[w]);
    }
    float* ob = out + (((size_t)n * FF + f) * TT + t) * VV;
    #pragma unroll
    for (int w = 0; w < VV; w += 4)
        *reinterpret_cast<float4*>(ob + w) = make_float4(o[w], o[w+1], o[w+2], o[w+3]);
}

extern "C" void kernel_launch(void* const* d_in, const int* in_sizes, int n_in,
                              void* d_out, int out_size, void* d_ws, size_t ws_size,
                              hipStream_t stream) {
    const float* x = (const float*)d_in[0];
    const float* a = (const float*)d_in[1];
    const float* W = (const float*)d_in[2];
    const float* b = (const float*)d_in[3];

    float* out   = (float*)d_out;
    float* out_a = out + (size_t)NN * FF * TT * VV;

    const size_t wt_bytes = (size_t)FF * CC * sizeof(_Float16);  // 131072

    if (ws_size >= wt_bytes) {
        _Float16* Wt = (_Float16*)d_ws;
        wt_prep_kernel<<<dim3(CC), dim3(FF), 0, stream>>>(W, Wt);
        sgcn_mfma12_kernel<<<dim3(NN * (TT / (TB * NCH))), dim3(512), 0, stream>>>(x, a, Wt, b, out, out_a);
    } else {
        sgcn_fused_kernel<<<dim3(NN * TT), dim3(256), 0, stream>>>(x, a, W, b, out, out_a);
    }
}